// Round 13
// baseline (744.917 us; speedup 1.0000x reference)
//
#include <hip/hip_runtime.h>

typedef __attribute__((ext_vector_type(8))) short short8;
typedef __attribute__((ext_vector_type(4))) float f32x4;
typedef __attribute__((ext_vector_type(2))) unsigned u32x2;

#define NN 4096
#define BN_EPS 1e-3f

__device__ inline unsigned short f2bf(float f) {
    unsigned u = __builtin_bit_cast(unsigned, f);
    return (unsigned short)((u + 0x7fffu + ((u >> 16) & 1u)) >> 16);
}
__device__ inline float bf2f(unsigned short h) {
    return __builtin_bit_cast(float, ((unsigned)h) << 16);
}

// ---------------------------------------------------------------------------
// gcn: x_l[b][n][c] = BN(relu(sum_m adj[b][n][m] * T[b][m][c] + bias[c]))
// tT is bf16 [b][c][m]. Block: 256 thr = 16 node-pairs x 16 feature-quads
// (32 nodes x 64 c per block). T staged per 64-m chunk into LDS [m][c];
// adj rows read directly from global (L1-broadcast across the 16 cq lanes).
// x_l output is bf16 [b][n][c] (intermediate). Grid: 4 x 128 = 512 blocks.
// ---------------------------------------------------------------------------
__global__ __launch_bounds__(256) void h72_gcn(
    const float* __restrict__ adj, const unsigned short* __restrict__ tT,
    const float* __restrict__ bias, const float* __restrict__ gamma,
    const float* __restrict__ beta, const float* __restrict__ mean,
    const float* __restrict__ var, unsigned short* __restrict__ xout)
{
    __shared__ float Tch[64][68];    // [m_local][c]
    const int tid = threadIdx.x;
    const int bid = blockIdx.x;
    const int b = bid >> 7, rb = bid & 127;
    const int np = tid >> 4;          // node pair 0..15
    const int cq = (tid & 15) * 4;    // feature quad
    const int n0 = rb * 32 + np * 2;
    const float* arow0 = adj + ((long)b * NN + n0) * (long)NN;
    const float* arow1 = arow0 + NN;
    const unsigned short* tb = tT + (long)b * 64 * (long)NN;

    f32x4 acc0 = {}, acc1 = {};
    for (int mc = 0; mc < NN; mc += 64) {
        __syncthreads();
        {
            const int c = tid >> 2;          // 0..63
            const int m4 = (tid & 3) * 16;   // 0,16,32,48
            const unsigned short* tp = tb + (long)c * NN + mc + m4;
            short8 v0 = *(const short8*)(tp);
            short8 v1 = *(const short8*)(tp + 8);
            for (int j = 0; j < 8; ++j) {
                Tch[m4 + j][c]     = bf2f((unsigned short)v0[j]);
                Tch[m4 + 8 + j][c] = bf2f((unsigned short)v1[j]);
            }
        }
        __syncthreads();
#pragma unroll 4
        for (int mm = 0; mm < 64; mm += 4) {
            f32x4 a0 = *(const f32x4*)(arow0 + mc + mm);
            f32x4 a1 = *(const f32x4*)(arow1 + mc + mm);
            for (int q = 0; q < 4; ++q) {
                f32x4 tv = *(const f32x4*)&Tch[mm + q][cq];
                acc0 += tv * a0[q];
                acc1 += tv * a1[q];
            }
        }
    }

    const f32x4 bi = *(const f32x4*)(bias + cq);
    const f32x4 mn = *(const f32x4*)(mean + cq);
    const f32x4 vr = *(const f32x4*)(var + cq);
    const f32x4 gm = *(const f32x4*)(gamma + cq);
    const f32x4 bt = *(const f32x4*)(beta + cq);
    float o0[4], o1[4];
    for (int q = 0; q < 4; ++q) {
        const float sc = gm[q] / sqrtf(vr[q] + BN_EPS);
        float h0 = acc0[q] + bi[q];
        h0 = h0 > 0.f ? h0 : 0.f;
        o0[q] = (h0 - mn[q]) * sc + bt[q];
        float h1 = acc1[q] + bi[q];
        h1 = h1 > 0.f ? h1 : 0.f;
        o1[q] = (h1 - mn[q]) * sc + bt[q];
    }
    unsigned short* xo = xout + ((long)b * NN + n0) * 64 + cq;
    u32x2 p0, p1;
    p0.x = (unsigned)f2bf(o0[0]) | ((unsigned)f2bf(o0[1]) << 16);
    p0.y = (unsigned)f2bf(o0[2]) | ((unsigned)f2bf(o0[3]) << 16);
    p1.x = (unsigned)f2bf(o1[0]) | ((unsigned)f2bf(o1[1]) << 16);
    p1.y = (unsigned)f2bf(o1[2]) | ((unsigned)f2bf(o1[3]) << 16);
    *(u32x2*)(xo) = p0;
    *(u32x2*)(xo + 64) = p1;
}

// ---------------------------------------------------------------------------
// Feature transform: tT[b][c][n] = sum_k xin[b][n][k] * W[k][c]  (bf16 out)
// ---------------------------------------------------------------------------
__global__ __launch_bounds__(256) void h72_feat32(
    const float* __restrict__ xin, const float* __restrict__ W,
    unsigned short* __restrict__ tT)
{
    __shared__ float xs[64][68];
    __shared__ float Ws[64][68];
    const int tid = threadIdx.x;
    const int bid = blockIdx.x;
    const int b = bid >> 6, nb = bid & 63;
    {
        const int rr = tid >> 2, kq = (tid & 3) * 16;
        const float* xp = xin + ((long)b * NN + nb * 64 + rr) * 64 + kq;
        const float* wp = W + rr * 64 + kq;
        for (int j = 0; j < 4; ++j) {
            *(f32x4*)&xs[rr][kq + j * 4] = *(const f32x4*)(xp + j * 4);
            *(f32x4*)&Ws[rr][kq + j * 4] = *(const f32x4*)(wp + j * 4);
        }
    }
    __syncthreads();
    const int c = tid >> 2, n0 = (tid & 3) * 16;
    float outv[16];
    for (int j = 0; j < 16; ++j) outv[j] = 0.f;
    for (int kt = 0; kt < 4; ++kt) {
        float wc[16];
#pragma unroll
        for (int kk = 0; kk < 16; ++kk) wc[kk] = Ws[kt * 16 + kk][c];
#pragma unroll
        for (int j = 0; j < 16; ++j)
#pragma unroll
            for (int kk = 0; kk < 16; ++kk)
                outv[j] += xs[n0 + j][kt * 16 + kk] * wc[kk];
    }
    unsigned short* tp = tT + ((long)b * 64 + c) * (long)NN + nb * 64 + n0;
#pragma unroll
    for (int j = 0; j < 16; j += 2)
        *(unsigned*)(tp + j) =
            (unsigned)f2bf(outv[j]) | ((unsigned)f2bf(outv[j + 1]) << 16);
}

__global__ __launch_bounds__(256) void h72_featbf(
    const unsigned short* __restrict__ xin, const float* __restrict__ W,
    unsigned short* __restrict__ tT)
{
    __shared__ float xs[64][68];
    __shared__ float Ws[64][68];
    const int tid = threadIdx.x;
    const int bid = blockIdx.x;
    const int b = bid >> 6, nb = bid & 63;
    {
        const int rr = tid >> 2, kq = (tid & 3) * 16;
        const unsigned short* xp = xin + ((long)b * NN + nb * 64 + rr) * 64 + kq;
        const float* wp = W + rr * 64 + kq;
        short8 v0 = *(const short8*)(xp);
        short8 v1 = *(const short8*)(xp + 8);
        for (int j = 0; j < 8; ++j) {
            xs[rr][kq + j]     = bf2f((unsigned short)v0[j]);
            xs[rr][kq + 8 + j] = bf2f((unsigned short)v1[j]);
        }
        for (int j = 0; j < 4; ++j)
            *(f32x4*)&Ws[rr][kq + j * 4] = *(const f32x4*)(wp + j * 4);
    }
    __syncthreads();
    const int c = tid >> 2, n0 = (tid & 3) * 16;
    float outv[16];
    for (int j = 0; j < 16; ++j) outv[j] = 0.f;
    for (int kt = 0; kt < 4; ++kt) {
        float wc[16];
#pragma unroll
        for (int kk = 0; kk < 16; ++kk) wc[kk] = Ws[kt * 16 + kk][c];
#pragma unroll
        for (int j = 0; j < 16; ++j)
#pragma unroll
            for (int kk = 0; kk < 16; ++kk)
                outv[j] += xs[n0 + j][kt * 16 + kk] * wc[kk];
    }
    unsigned short* tp = tT + ((long)b * 64 + c) * (long)NN + nb * 64 + n0;
#pragma unroll
    for (int j = 0; j < 16; j += 2)
        *(unsigned*)(tp + j) =
            (unsigned)f2bf(outv[j]) | ((unsigned)f2bf(outv[j + 1]) << 16);
}

// ---------------------------------------------------------------------------
// Final MLP: out = relu(concat(x1,x2,x3) @ Wl + bl) -> FLOAT32 output
// ---------------------------------------------------------------------------
__global__ __launch_bounds__(256) void h72_mlp(
    const unsigned short* __restrict__ x1, const unsigned short* __restrict__ x2,
    const unsigned short* __restrict__ x3, const float* __restrict__ Wl,
    const float* __restrict__ bl, float* __restrict__ out)
{
    __shared__ float hs[64][196];
    const int tid = threadIdx.x;
    const int bid = blockIdx.x;
    const int b = bid >> 6, nb = bid & 63;
    {
        const int rr = tid >> 2, kq = (tid & 3) * 16;
        const long base = ((long)b * NN + nb * 64 + rr) * 64 + kq;
        short8 u0 = *(const short8*)(x1 + base);
        short8 u1 = *(const short8*)(x1 + base + 8);
        short8 v0 = *(const short8*)(x2 + base);
        short8 v1 = *(const short8*)(x2 + base + 8);
        short8 w0 = *(const short8*)(x3 + base);
        short8 w1 = *(const short8*)(x3 + base + 8);
        for (int j = 0; j < 8; ++j) {
            hs[rr][  0 + kq + j]     = bf2f((unsigned short)u0[j]);
            hs[rr][  0 + kq + 8 + j] = bf2f((unsigned short)u1[j]);
            hs[rr][ 64 + kq + j]     = bf2f((unsigned short)v0[j]);
            hs[rr][ 64 + kq + 8 + j] = bf2f((unsigned short)v1[j]);
            hs[rr][128 + kq + j]     = bf2f((unsigned short)w0[j]);
            hs[rr][128 + kq + 8 + j] = bf2f((unsigned short)w1[j]);
        }
    }
    __syncthreads();
    const int c = tid >> 2, n0 = (tid & 3) * 16;
    float acc[16];
    const float blc = bl[c];
    for (int j = 0; j < 16; ++j) acc[j] = blc;
    for (int kt = 0; kt < 12; ++kt) {
        float wc[16];
#pragma unroll
        for (int kk = 0; kk < 16; ++kk) wc[kk] = Wl[(kt * 16 + kk) * 64 + c];
#pragma unroll
        for (int j = 0; j < 16; ++j)
#pragma unroll
            for (int kk = 0; kk < 16; ++kk)
                acc[j] += hs[n0 + j][kt * 16 + kk] * wc[kk];
    }
    float* op = out + ((long)b * NN + nb * 64 + n0) * 64 + c;
#pragma unroll
    for (int j = 0; j < 16; ++j) {
        float v2 = acc[j] > 0.f ? acc[j] : 0.f;
        op[j * 64] = v2;
    }
}

// ---------------------------------------------------------------------------
extern "C" void kernel_launch(void* const* d_in, const int* in_sizes, int n_in,
                              void* d_out, int out_size, void* d_ws, size_t ws_size,
                              hipStream_t stream)
{
    (void)in_sizes; (void)n_in; (void)out_size; (void)ws_size;
    const float* x   = (const float*)d_in[0];
    const float* adj = (const float*)d_in[1];
    const float* W1  = (const float*)d_in[2];
    const float* b1  = (const float*)d_in[3];
    const float* g1  = (const float*)d_in[4];
    const float* be1 = (const float*)d_in[5];
    const float* m1  = (const float*)d_in[6];
    const float* v1  = (const float*)d_in[7];
    const float* W2  = (const float*)d_in[8];
    const float* b2  = (const float*)d_in[9];
    const float* g2  = (const float*)d_in[10];
    const float* be2 = (const float*)d_in[11];
    const float* m2  = (const float*)d_in[12];
    const float* v2  = (const float*)d_in[13];
    const float* W3  = (const float*)d_in[14];
    const float* b3  = (const float*)d_in[15];
    const float* g3  = (const float*)d_in[16];
    const float* be3 = (const float*)d_in[17];
    const float* m3  = (const float*)d_in[18];
    const float* v3  = (const float*)d_in[19];
    const float* Wl  = (const float*)d_in[20];
    const float* bl  = (const float*)d_in[21];

    // OUTPUT IS FLOAT32: 1048576 floats = 4 MB.
    float* out = (float*)d_out;
    // tT (bf16, 2 MB) lives in d_out's SECOND half; fully rewritten before
    // each use, and h72_mlp overwrites all of d_out last -> deterministic.
    unsigned short* tT = (unsigned short*)(out + 524288);

    char* ws = (char*)d_ws;
    unsigned short* x1 = (unsigned short*)(ws);
    unsigned short* x2 = (unsigned short*)(ws + 2097152);
    unsigned short* x3 = (unsigned short*)(ws + 4194304);

    h72_feat32<<<256, 256, 0, stream>>>(x, W1, tT);
    h72_gcn<<<512, 256, 0, stream>>>(adj, tT, b1, g1, be1, m1, v1, x1);

    h72_featbf<<<256, 256, 0, stream>>>(x1, W2, tT);
    h72_gcn<<<512, 256, 0, stream>>>(adj, tT, b2, g2, be2, m2, v2, x2);

    h72_featbf<<<256, 256, 0, stream>>>(x2, W3, tT);
    h72_gcn<<<512, 256, 0, stream>>>(adj, tT, b3, g3, be3, m3, v3, x3);

    h72_mlp<<<256, 256, 0, stream>>>(x1, x2, x3, Wl, bl, out);
}

// Round 14
// 347.182 us; speedup vs baseline: 2.1456x; 2.1456x over previous
//
#include <hip/hip_runtime.h>

typedef __attribute__((ext_vector_type(8))) short short8;
typedef __attribute__((ext_vector_type(4))) float f32x4;
typedef __attribute__((ext_vector_type(2))) unsigned u32x2;

#define NN 4096
#define BN_EPS 1e-3f

__device__ inline unsigned short f2bf(float f) {
    unsigned u = __builtin_bit_cast(unsigned, f);
    return (unsigned short)((u + 0x7fffu + ((u >> 16) & 1u)) >> 16);
}
__device__ inline float bf2f(unsigned short h) {
    return __builtin_bit_cast(float, ((unsigned)h) << 16);
}

// ---------------------------------------------------------------------------
// MFMA gcn: S = adj[b] @ T[b]; computed as S^T via mfma(A = T^T strip,
// B = adj strip) — both operands k-contiguous with the SAME (lane,elem)->m
// map, so the contraction is layout-robust. 256 thr = 4 waves on the same
// 16 output rows, 4-way K-split (1024 each). LDS reduce + fused
// bias/ReLU/BN epilogue. xout = bf16 [b][n][c]. Verified-correct math
// (rounds 3-5); output dtype was the only historical bug.
// ---------------------------------------------------------------------------
__global__ __launch_bounds__(256) void i72_gcn(
    const float* __restrict__ adj, const unsigned short* __restrict__ tT,
    const float* __restrict__ bias, const float* __restrict__ gamma,
    const float* __restrict__ beta, const float* __restrict__ mean,
    const float* __restrict__ var, unsigned short* __restrict__ xout)
{
    const int tid = threadIdx.x;
    const int s = tid >> 6, lane = tid & 63;
    const int rl = lane & 15, grp = lane >> 4;
    const int bid = blockIdx.x;
    const int b = bid >> 8, rb = bid & 255;
    const int row = rb * 16 + rl;

    const float* arow = adj + ((long)b * NN + row) * (long)NN;
    const unsigned short* t0 = tT + ((long)b * 64 + rl) * (long)NN;
    const unsigned short* t1 = t0 + 16 * (long)NN;
    const unsigned short* t2 = t0 + 32 * (long)NN;
    const unsigned short* t3 = t0 + 48 * (long)NN;
    const int m0 = s * 1024 + grp * 8;

    f32x4 a0 = {}, a1 = {}, a2 = {}, a3 = {};
    for (int it = 0; it < 32; ++it) {
        const int m = m0 + it * 32;
        short8 A0 = *(const short8*)(t0 + m);
        short8 A1 = *(const short8*)(t1 + m);
        short8 A2 = *(const short8*)(t2 + m);
        short8 A3 = *(const short8*)(t3 + m);
        f32x4 f0 = *(const f32x4*)(arow + m);
        f32x4 f1 = *(const f32x4*)(arow + m + 4);
        short8 B;
        B[0] = (short)f2bf(f0.x); B[1] = (short)f2bf(f0.y);
        B[2] = (short)f2bf(f0.z); B[3] = (short)f2bf(f0.w);
        B[4] = (short)f2bf(f1.x); B[5] = (short)f2bf(f1.y);
        B[6] = (short)f2bf(f1.z); B[7] = (short)f2bf(f1.w);
        a0 = __builtin_amdgcn_mfma_f32_16x16x32_bf16(A0, B, a0, 0, 0, 0);
        a1 = __builtin_amdgcn_mfma_f32_16x16x32_bf16(A1, B, a1, 0, 0, 0);
        a2 = __builtin_amdgcn_mfma_f32_16x16x32_bf16(A2, B, a2, 0, 0, 0);
        a3 = __builtin_amdgcn_mfma_f32_16x16x32_bf16(A3, B, a3, 0, 0, 0);
    }

    // D layout (m89, probe-confirmed r4/r5): col=lane&15 -> node rl;
    // row=(lane>>4)*4+q -> feature grp*4+q (within each 16-feature group).
    __shared__ float red[4][16][68];   // [kwave][node][feature]
    *(f32x4*)&red[s][rl][ 0 + grp * 4] = a0;
    *(f32x4*)&red[s][rl][16 + grp * 4] = a1;
    *(f32x4*)&red[s][rl][32 + grp * 4] = a2;
    *(f32x4*)&red[s][rl][48 + grp * 4] = a3;
    __syncthreads();

    const int r2 = tid >> 4, cq = (tid & 15) * 4;
    f32x4 v = *(const f32x4*)&red[0][r2][cq];
    v += *(const f32x4*)&red[1][r2][cq];
    v += *(const f32x4*)&red[2][r2][cq];
    v += *(const f32x4*)&red[3][r2][cq];

    f32x4 bi = *(const f32x4*)(bias + cq);
    f32x4 mn = *(const f32x4*)(mean + cq);
    f32x4 vr = *(const f32x4*)(var + cq);
    f32x4 gm = *(const f32x4*)(gamma + cq);
    f32x4 bt = *(const f32x4*)(beta + cq);
    float o[4];
    for (int q = 0; q < 4; ++q) {
        float h = v[q] + bi[q];
        h = h > 0.f ? h : 0.f;
        o[q] = (h - mn[q]) * (gm[q] / sqrtf(vr[q] + BN_EPS)) + bt[q];
    }
    u32x2 o2;
    o2.x = (unsigned)f2bf(o[0]) | ((unsigned)f2bf(o[1]) << 16);
    o2.y = (unsigned)f2bf(o[2]) | ((unsigned)f2bf(o[3]) << 16);
    *(u32x2*)(xout + ((long)b * NN + rb * 16 + r2) * 64 + cq) = o2;
}

// ---------------------------------------------------------------------------
// Feature transform: tT[b][c][n] = sum_k xin[b][n][k] * W[k][c]  (bf16 out)
// ---------------------------------------------------------------------------
__global__ __launch_bounds__(256) void h72_feat32(
    const float* __restrict__ xin, const float* __restrict__ W,
    unsigned short* __restrict__ tT)
{
    __shared__ float xs[64][68];
    __shared__ float Ws[64][68];
    const int tid = threadIdx.x;
    const int bid = blockIdx.x;
    const int b = bid >> 6, nb = bid & 63;
    {
        const int rr = tid >> 2, kq = (tid & 3) * 16;
        const float* xp = xin + ((long)b * NN + nb * 64 + rr) * 64 + kq;
        const float* wp = W + rr * 64 + kq;
        for (int j = 0; j < 4; ++j) {
            *(f32x4*)&xs[rr][kq + j * 4] = *(const f32x4*)(xp + j * 4);
            *(f32x4*)&Ws[rr][kq + j * 4] = *(const f32x4*)(wp + j * 4);
        }
    }
    __syncthreads();
    const int c = tid >> 2, n0 = (tid & 3) * 16;
    float outv[16];
    for (int j = 0; j < 16; ++j) outv[j] = 0.f;
    for (int kt = 0; kt < 4; ++kt) {
        float wc[16];
#pragma unroll
        for (int kk = 0; kk < 16; ++kk) wc[kk] = Ws[kt * 16 + kk][c];
#pragma unroll
        for (int j = 0; j < 16; ++j)
#pragma unroll
            for (int kk = 0; kk < 16; ++kk)
                outv[j] += xs[n0 + j][kt * 16 + kk] * wc[kk];
    }
    unsigned short* tp = tT + ((long)b * 64 + c) * (long)NN + nb * 64 + n0;
#pragma unroll
    for (int j = 0; j < 16; j += 2)
        *(unsigned*)(tp + j) =
            (unsigned)f2bf(outv[j]) | ((unsigned)f2bf(outv[j + 1]) << 16);
}

__global__ __launch_bounds__(256) void h72_featbf(
    const unsigned short* __restrict__ xin, const float* __restrict__ W,
    unsigned short* __restrict__ tT)
{
    __shared__ float xs[64][68];
    __shared__ float Ws[64][68];
    const int tid = threadIdx.x;
    const int bid = blockIdx.x;
    const int b = bid >> 6, nb = bid & 63;
    {
        const int rr = tid >> 2, kq = (tid & 3) * 16;
        const unsigned short* xp = xin + ((long)b * NN + nb * 64 + rr) * 64 + kq;
        const float* wp = W + rr * 64 + kq;
        short8 v0 = *(const short8*)(xp);
        short8 v1 = *(const short8*)(xp + 8);
        for (int j = 0; j < 8; ++j) {
            xs[rr][kq + j]     = bf2f((unsigned short)v0[j]);
            xs[rr][kq + 8 + j] = bf2f((unsigned short)v1[j]);
        }
        for (int j = 0; j < 4; ++j)
            *(f32x4*)&Ws[rr][kq + j * 4] = *(const f32x4*)(wp + j * 4);
    }
    __syncthreads();
    const int c = tid >> 2, n0 = (tid & 3) * 16;
    float outv[16];
    for (int j = 0; j < 16; ++j) outv[j] = 0.f;
    for (int kt = 0; kt < 4; ++kt) {
        float wc[16];
#pragma unroll
        for (int kk = 0; kk < 16; ++kk) wc[kk] = Ws[kt * 16 + kk][c];
#pragma unroll
        for (int j = 0; j < 16; ++j)
#pragma unroll
            for (int kk = 0; kk < 16; ++kk)
                outv[j] += xs[n0 + j][kt * 16 + kk] * wc[kk];
    }
    unsigned short* tp = tT + ((long)b * 64 + c) * (long)NN + nb * 64 + n0;
#pragma unroll
    for (int j = 0; j < 16; j += 2)
        *(unsigned*)(tp + j) =
            (unsigned)f2bf(outv[j]) | ((unsigned)f2bf(outv[j + 1]) << 16);
}

// ---------------------------------------------------------------------------
// Final MLP: out = relu(concat(x1,x2,x3) @ Wl + bl) -> FLOAT32 output
// ---------------------------------------------------------------------------
__global__ __launch_bounds__(256) void h72_mlp(
    const unsigned short* __restrict__ x1, const unsigned short* __restrict__ x2,
    const unsigned short* __restrict__ x3, const float* __restrict__ Wl,
    const float* __restrict__ bl, float* __restrict__ out)
{
    __shared__ float hs[64][196];
    const int tid = threadIdx.x;
    const int bid = blockIdx.x;
    const int b = bid >> 6, nb = bid & 63;
    {
        const int rr = tid >> 2, kq = (tid & 3) * 16;
        const long base = ((long)b * NN + nb * 64 + rr) * 64 + kq;
        short8 u0 = *(const short8*)(x1 + base);
        short8 u1 = *(const short8*)(x1 + base + 8);
        short8 v0 = *(const short8*)(x2 + base);
        short8 v1 = *(const short8*)(x2 + base + 8);
        short8 w0 = *(const short8*)(x3 + base);
        short8 w1 = *(const short8*)(x3 + base + 8);
        for (int j = 0; j < 8; ++j) {
            hs[rr][  0 + kq + j]     = bf2f((unsigned short)u0[j]);
            hs[rr][  0 + kq + 8 + j] = bf2f((unsigned short)u1[j]);
            hs[rr][ 64 + kq + j]     = bf2f((unsigned short)v0[j]);
            hs[rr][ 64 + kq + 8 + j] = bf2f((unsigned short)v1[j]);
            hs[rr][128 + kq + j]     = bf2f((unsigned short)w0[j]);
            hs[rr][128 + kq + 8 + j] = bf2f((unsigned short)w1[j]);
        }
    }
    __syncthreads();
    const int c = tid >> 2, n0 = (tid & 3) * 16;
    float acc[16];
    const float blc = bl[c];
    for (int j = 0; j < 16; ++j) acc[j] = blc;
    for (int kt = 0; kt < 12; ++kt) {
        float wc[16];
#pragma unroll
        for (int kk = 0; kk < 16; ++kk) wc[kk] = Wl[(kt * 16 + kk) * 64 + c];
#pragma unroll
        for (int j = 0; j < 16; ++j)
#pragma unroll
            for (int kk = 0; kk < 16; ++kk)
                acc[j] += hs[n0 + j][kt * 16 + kk] * wc[kk];
    }
    float* op = out + ((long)b * NN + nb * 64 + n0) * 64 + c;
#pragma unroll
    for (int j = 0; j < 16; ++j) {
        float v2 = acc[j] > 0.f ? acc[j] : 0.f;
        op[j * 64] = v2;
    }
}

// ---------------------------------------------------------------------------
extern "C" void kernel_launch(void* const* d_in, const int* in_sizes, int n_in,
                              void* d_out, int out_size, void* d_ws, size_t ws_size,
                              hipStream_t stream)
{
    (void)in_sizes; (void)n_in; (void)out_size; (void)ws_size;
    const float* x   = (const float*)d_in[0];
    const float* adj = (const float*)d_in[1];
    const float* W1  = (const float*)d_in[2];
    const float* b1  = (const float*)d_in[3];
    const float* g1  = (const float*)d_in[4];
    const float* be1 = (const float*)d_in[5];
    const float* m1  = (const float*)d_in[6];
    const float* v1  = (const float*)d_in[7];
    const float* W2  = (const float*)d_in[8];
    const float* b2  = (const float*)d_in[9];
    const float* g2  = (const float*)d_in[10];
    const float* be2 = (const float*)d_in[11];
    const float* m2  = (const float*)d_in[12];
    const float* v2  = (const float*)d_in[13];
    const float* W3  = (const float*)d_in[14];
    const float* b3  = (const float*)d_in[15];
    const float* g3  = (const float*)d_in[16];
    const float* be3 = (const float*)d_in[17];
    const float* m3  = (const float*)d_in[18];
    const float* v3  = (const float*)d_in[19];
    const float* Wl  = (const float*)d_in[20];
    const float* bl  = (const float*)d_in[21];

    // OUTPUT IS FLOAT32: 1048576 floats = 4 MB.
    float* out = (float*)d_out;
    // tT (bf16, 2 MB) lives in d_out's SECOND half; fully rewritten before
    // each use, and h72_mlp overwrites all of d_out last -> deterministic.
    unsigned short* tT = (unsigned short*)(out + 524288);

    char* ws = (char*)d_ws;
    unsigned short* x1 = (unsigned short*)(ws);
    unsigned short* x2 = (unsigned short*)(ws + 2097152);
    unsigned short* x3 = (unsigned short*)(ws + 4194304);

    h72_feat32<<<256, 256, 0, stream>>>(x, W1, tT);
    i72_gcn<<<1024, 256, 0, stream>>>(adj, tT, b1, g1, be1, m1, v1, x1);

    h72_featbf<<<256, 256, 0, stream>>>(x1, W2, tT);
    i72_gcn<<<1024, 256, 0, stream>>>(adj, tT, b2, g2, be2, m2, v2, x2);

    h72_featbf<<<256, 256, 0, stream>>>(x2, W3, tT);
    i72_gcn<<<1024, 256, 0, stream>>>(adj, tT, b3, g3, be3, m3, v3, x3);

    h72_mlp<<<256, 256, 0, stream>>>(x1, x2, x3, Wl, bl, out);
}